// Round 10
// baseline (126.676 us; speedup 1.0000x reference)
//
#include <hip/hip_runtime.h>
#include <math.h>

#define NN 8
#define CC 256        // channels per tensor (concat input has 2*CC = 512)
#define HH 48
#define WW 48
#define HW 2304       // 48*48
#define OCONV 18      // offset-conv output channels (2*K)
#define KTAP 9        // deform taps
#define G1 4          // split-K groups for offset conv (512/4 = 128 ch/group)
#define NSZ (NN * OCONV * HW)   // 331776
#define MM 96         // padded deform-GEMM rows (81 used)
#define PSTR 2312     // qsT site stride: 2304 sites + 8 zero-sites (pad)

typedef __attribute__((ext_vector_type(8))) short short8;   // 8 bf16 (4 VGPRs)
typedef __attribute__((ext_vector_type(16))) float f32x16;  // 32x32 MFMA acc

static __device__ __forceinline__ unsigned short f2bf(float f) {
  unsigned u = __float_as_uint(f);
  unsigned r = (u + 0x7fffu + ((u >> 16) & 1u)) >> 16;   // round-to-nearest-even
  return (unsigned short)r;
}

// ---------------------------------------------------------------------------
// Kernel 0a: w_off[18][512][5][5] -> A-frags Wm2, addr (shorts):
// t*16384 + g*4096 + kk*512 + half*256 + lane*8 + j ; c = g*128+kk*16+half*8+j
// ---------------------------------------------------------------------------
__global__ __launch_bounds__(256) void prep_wm2_kernel(
    const float* __restrict__ w_off, unsigned short* __restrict__ Wm2) {
  const int i = blockIdx.x * 256 + threadIdx.x;
  if (i >= 25 * 16384) return;
  const int j    = i & 7;
  const int l    = (i >> 3) & 31;
  const int half = (i >> 8) & 1;
  const int kk   = (i >> 9) & 7;
  const int g    = (i >> 12) & 3;
  const int t    = i >> 14;          // 0..24
  const int c = g * 128 + kk * 16 + half * 8 + j;
  float v = 0.f;
  if (l < OCONV) v = w_off[(size_t)(l * (2 * CC) + c) * 25 + t];
  Wm2[i] = f2bf(v);
}

// ---------------------------------------------------------------------------
// Kernel 0b: w_kernel[9][256][9] -> wkm A-frags (rows m=k*9+o, pad 96)
// ---------------------------------------------------------------------------
__global__ __launch_bounds__(256) void prep_wkm_kernel(
    const float* __restrict__ w_kernel, unsigned short* __restrict__ wkm) {
  const int i = blockIdx.x * 256 + threadIdx.x;
  if (i >= 3 * 16 * 2 * 32 * 8) return;
  const int j    = i & 7;
  const int r    = (i >> 3) & 31;
  const int half = (i >> 8) & 1;
  const int cb   = (i >> 9) & 15;
  const int mt   = i >> 13;
  const int m = mt * 32 + r;
  const int c = cb * 16 + half * 8 + j;
  float v = 0.f;
  if (m < 81) {
    const int k = m / 9, o = m % 9;
    v = w_kernel[(size_t)(o * CC + c) * KTAP + k];
  }
  wkm[i] = f2bf(v);
}

// ---------------------------------------------------------------------------
// Kernel 1: transpose query+support -> qsT[n][site][512] bf16 channel-last,
// c<256 = query, c>=256 = support. Sites 2304..2311 zeroed (OOB taps land
// there). XCD-pinned by n.
// ---------------------------------------------------------------------------
__global__ __launch_bounds__(256) void transpose_kernel(
    const float* __restrict__ support, const float* __restrict__ query,
    unsigned short* __restrict__ qsT) {
  const int bid = blockIdx.x;         // 9216 = 8n * 72pt * 16ct
  const int n    = bid & 7;           // XCD pin
  const int rest = bid >> 3;
  const int pt = rest % 72;
  const int ct = rest / 72;           // 0..15 (ct<8: query, else support)
  const int p0 = pt * 32;
  const int tid = threadIdx.x;

  __shared__ float tile[32][33];

  const float* plane = ((ct < 8) ? query : support) +
                       ((size_t)n * CC + (ct & 7) * 32) * HW;
#pragma unroll
  for (int j = 0; j < 4; ++j) {
    const int idx = tid + j * 256;
    const int cc = idx >> 5, pp = idx & 31;
    tile[pp][cc] = plane[(size_t)cc * HW + p0 + pp];
  }
  __syncthreads();

#pragma unroll
  for (int j = 0; j < 2; ++j) {
    const int idx = tid + j * 256;
    const int pp = idx >> 4, cp = idx & 15;
    const unsigned lo = f2bf(tile[pp][2 * cp]);
    const unsigned hi = f2bf(tile[pp][2 * cp + 1]);
    unsigned* dst = (unsigned*)(qsT + ((size_t)n * PSTR + p0 + pp) * 512 + ct * 32);
    dst[cp] = lo | (hi << 16);
  }

  // zero-sites for this (n, ct) slice
  if (pt == 0 && tid < 128) {
    const int zs = 2304 + (tid >> 4);
    unsigned* dst = (unsigned*)(qsT + ((size_t)n * PSTR + zs) * 512 + ct * 32);
    dst[tid & 15] = 0u;
  }
}

// ---------------------------------------------------------------------------
// Kernel 2: offset conv, no-LDS implicit GEMM. Block = 4 waves = 4 K-groups
// (g = wave id, K=128 each); wave computes 32 outs x 32 sites over 25 taps.
// B-frags: direct 16B loads from qsT (zero-site for OOB). A-frags: Wm2.
// offs_part[G1][N][18][HW] partials. XCD-pinned by n.
// ---------------------------------------------------------------------------
__global__ __launch_bounds__(256, 2) void offset_conv_mfma(
    const unsigned short* __restrict__ qsT,
    const unsigned short* __restrict__ Wm2, float* __restrict__ offs_part) {
  const int bid = blockIdx.x;        // 576 = 72 st * 8 n
  const int n  = bid & 7;            // XCD pin
  const int st = bid >> 3;           // 0..71
  const int tid = threadIdx.x;
  const int g = tid >> 6;            // wave = K-group 0..3
  const int l = tid & 63;
  const int lane31 = l & 31;
  const int half = l >> 5;
  const int s = st * 32 + lane31;
  const int y = s / 48, x = s % 48;

  const unsigned short* bbase = qsT + (size_t)n * PSTR * 512 + g * 128 + half * 8;
  const unsigned short* abase = Wm2 + g * 4096 + half * 256 + lane31 * 8;

  f32x16 acc = {0.f, 0.f, 0.f, 0.f, 0.f, 0.f, 0.f, 0.f,
                0.f, 0.f, 0.f, 0.f, 0.f, 0.f, 0.f, 0.f};

  for (int u = 0; u < 5; ++u) {
    const int yy = y + u - 2;
    for (int v = 0; v < 5; ++v) {
      const int xx = x + v - 2;
      const bool ok = ((unsigned)yy < 48u) && ((unsigned)xx < 48u);
      const int p2 = ok ? (yy * 48 + xx) : 2304;     // zero-site if OOB
      const unsigned short* bsrc = bbase + (size_t)p2 * 512;
      const unsigned short* asrc = abase + (size_t)(u * 5 + v) * 16384;
#pragma unroll
      for (int kk = 0; kk < 8; ++kk) {
        const short8 b = *(const short8*)(bsrc + kk * 16);
        const short8 a = *(const short8*)(asrc + kk * 512);
        acc = __builtin_amdgcn_mfma_f32_32x32x16_bf16(a, b, acc, 0, 0, 0);
      }
    }
  }

  float* dst = offs_part + ((size_t)(g * NN + n) * OCONV) * HW;
#pragma unroll
  for (int r = 0; r < 16; ++r) {
    const int o = (r & 3) + 8 * (r >> 2) + 4 * half;
    if (o < OCONV) dst[(size_t)o * HW + s] = acc[r];
  }
}

// ---------------------------------------------------------------------------
// Kernel 3: fold split-K partials + precompute bilinear params.
// par[n][k][p][8]: {w00,w01,w10,w11 (f32), a00,a01,a10,a11 (int)}. XCD-pinned.
// ---------------------------------------------------------------------------
__global__ __launch_bounds__(256) void param_kernel(
    const float* __restrict__ offs_part, float* __restrict__ par) {
  const int n  = blockIdx.x & 7;       // XCD pin
  const int j  = blockIdx.x >> 3;      // 0..80
  const int il = j * 256 + threadIdx.x;
  const int p = il % HW;
  const int k = il / HW;
  const int y = p / WW, x = p % WW;

  float dy = 0.f, dx = 0.f;
#pragma unroll
  for (int g = 0; g < G1; ++g) {
    const float* base = offs_part + ((size_t)(g * NN + n) * OCONV + 2 * k) * HW + p;
    dy += base[0];
    dx += base[HW];
  }
  const float sy = (float)(y + k / 3 - 1) + dy;
  const float sx = (float)(x + k % 3 - 1) + dx;
  const float y0 = floorf(sy), x0 = floorf(sx);
  const float ly = sy - y0,  lx = sx - x0;
  const float y1 = y0 + 1.f, x1 = x0 + 1.f;
  const float vy0 = (y0 >= 0.f && y0 <= (float)(HH - 1)) ? 1.f : 0.f;
  const float vy1 = (y1 >= 0.f && y1 <= (float)(HH - 1)) ? 1.f : 0.f;
  const float vx0 = (x0 >= 0.f && x0 <= (float)(WW - 1)) ? 1.f : 0.f;
  const float vx1 = (x1 >= 0.f && x1 <= (float)(WW - 1)) ? 1.f : 0.f;
  const int yi0 = min(max((int)y0, 0), HH - 1);
  const int yi1 = min(max((int)y1, 0), HH - 1);
  const int xi0 = min(max((int)x0, 0), WW - 1);
  const int xi1 = min(max((int)x1, 0), WW - 1);

  float* d = par + ((size_t)n * KTAP * HW + il) * 8;
  d[0] = (1.f - ly) * (1.f - lx) * vy0 * vx0;
  d[1] = (1.f - ly) * lx * vy0 * vx1;
  d[2] = ly * (1.f - lx) * vy1 * vx0;
  d[3] = ly * lx * vy1 * vx1;
  int* di = (int*)d;
  di[4] = yi0 * WW + xi0;
  di[5] = yi0 * WW + xi1;
  di[6] = yi1 * WW + xi0;
  di[7] = yi1 * WW + xi1;
}

// ---------------------------------------------------------------------------
// Kernel 4: D[n][m][site] = sum_c wk[o][c][k] * sup[n][c][site], m=k*9+o.
// B = support half of qsT (ch 256..511). XCD-pinned.
// ---------------------------------------------------------------------------
__global__ __launch_bounds__(256) void deform_gemm(
    const unsigned short* __restrict__ qsT, const unsigned short* __restrict__ wkm,
    float* __restrict__ D) {
  const int bid = blockIdx.x;
  const int n    = bid & 7;           // XCD pin
  const int rest = bid >> 3;          // 0..53
  const int tid = threadIdx.x;
  const int w = tid >> 6;
  const int wid = rest * 4 + w;       // 0..215
  const int st = wid % 72;            // site tile
  const int mt = wid / 72;            // m tile 0..2
  const int l = tid & 63;
  const int lane31 = l & 31;
  const int half = l >> 5;
  const int site0 = st * 32;

  const unsigned short* bsrc =
      qsT + ((size_t)n * PSTR + site0 + lane31) * 512 + 256 + half * 8;
  const unsigned short* asrc = wkm + (size_t)(half * 32 + lane31) * 8;

  f32x16 acc = {0.f, 0.f, 0.f, 0.f, 0.f, 0.f, 0.f, 0.f,
                0.f, 0.f, 0.f, 0.f, 0.f, 0.f, 0.f, 0.f};

#pragma unroll
  for (int cb = 0; cb < 16; ++cb) {
    const short8 b = *(const short8*)(bsrc + cb * 16);
    const short8 a = *(const short8*)(asrc + (size_t)((mt * 16 + cb) * 2) * 256);
    acc = __builtin_amdgcn_mfma_f32_32x32x16_bf16(a, b, acc, 0, 0, 0);
  }

  float* Dn = D + (size_t)n * MM * HW;
#pragma unroll
  for (int r = 0; r < 16; ++r) {
    const int m = mt * 32 + (r & 3) + 8 * (r >> 2) + 4 * half;
    Dn[(size_t)m * HW + site0 + lane31] = acc[r];
  }
}

// ---------------------------------------------------------------------------
// Kernel 5: combine + sigmoid. One thread per output element. XCD-pinned.
// ---------------------------------------------------------------------------
__global__ __launch_bounds__(256) void deform_combine(
    const float* __restrict__ D, const float* __restrict__ par,
    float* __restrict__ out) {
  const int bid = blockIdx.x;          // 648 = 81 * 8n
  const int n  = bid & 7;              // XCD pin
  const int rr = bid >> 3;             // 0..80
  const int o  = rr / 9;
  const int p  = (rr % 9) * 256 + threadIdx.x;

  const float* Dn = D + (size_t)n * MM * HW;
  const float* pb = par + ((size_t)n * KTAP * HW + p) * 8;

  float s = 0.f;
#pragma unroll
  for (int k = 0; k < KTAP; ++k) {
    const float4 wv = *(const float4*)(pb + (size_t)k * HW * 8);
    const int4  av = *(const int4*)(pb + (size_t)k * HW * 8 + 4);
    const float* base = Dn + (size_t)(k * 9 + o) * HW;
    s += wv.x * base[av.x] + wv.y * base[av.y] +
         wv.z * base[av.z] + wv.w * base[av.w];
  }
  out[((size_t)n * KTAP + o) * HW + p] = 1.f / (1.f + __expf(-s));
}

extern "C" void kernel_launch(void* const* d_in, const int* in_sizes, int n_in,
                              void* d_out, int out_size, void* d_ws, size_t ws_size,
                              hipStream_t stream) {
  const float* support  = (const float*)d_in[0];
  const float* query    = (const float*)d_in[1];
  const float* w_off    = (const float*)d_in[2];
  const float* w_kernel = (const float*)d_in[3];
  float* out = (float*)d_out;

  // ws layout (float units), ~32.2 MB total:
  // [qsT 18.9MB][par 5.3MB][Wm2 0.82MB][wkm 0.1MB][X: offs_part 5.3MB / D 7.1MB]
  float* base = (float*)d_ws;
  unsigned short* qsT = (unsigned short*)base;                  // 8*PSTR*512 bf16
  float* par = base + (size_t)NN * PSTR * 512 / 2;              // NN*9*HW*8 f
  float* tail = par + (size_t)NN * KTAP * HW * 8;
  unsigned short* Wm2 = (unsigned short*)tail;                  // 409600 bf16 = 204800 f
  unsigned short* wkm = (unsigned short*)(tail + 204800);       // 49152 bf16 = 24576 f
  float* X = tail + 204800 + 24576;
  float* offs_part = X;                                         // G1*NSZ f (early)
  float* D = X;                                                 // NN*MM*HW f (late, aliases)

  prep_wm2_kernel<<<(25 * 16384 + 255) / 256, 256, 0, stream>>>(w_off, Wm2);
  prep_wkm_kernel<<<(3 * 16 * 2 * 32 * 8 + 255) / 256, 256, 0, stream>>>(w_kernel, wkm);
  transpose_kernel<<<8 * 72 * 16, 256, 0, stream>>>(support, query, qsT);
  offset_conv_mfma<<<72 * 8, 256, 0, stream>>>(qsT, Wm2, offs_part);
  param_kernel<<<81 * 8, 256, 0, stream>>>(offs_part, par);
  deform_gemm<<<54 * 8, 256, 0, stream>>>(qsT, wkm, D);   // D aliases offs_part (dead)
  deform_combine<<<81 * 8, 256, 0, stream>>>(D, par, out);
}

// Round 11
// 74.761 us; speedup vs baseline: 1.6944x; 1.6944x over previous
//
#include <hip/hip_runtime.h>
#include <math.h>

#define NN 8
#define CC 256        // channels per tensor (concat input has 2*CC = 512)
#define HH 48
#define WW 48
#define HW 2304       // 48*48
#define OCONV 18      // offset-conv output channels (2*K)
#define KTAP 9        // deform taps
#define G1 8          // split-K groups for offset conv (512/8 = 64 ch/group)
#define NSZ (NN * OCONV * HW)   // 331776
#define MM 96         // padded deform-GEMM rows (81 used)
#define QSTR 2312     // qsT3 sites per cg-plane: 2304 + 8 zero-sites
#define NCG 64        // 512 ch / 8

typedef __attribute__((ext_vector_type(8))) short short8;   // 8 bf16 (4 VGPRs)
typedef __attribute__((ext_vector_type(16))) float f32x16;  // 32x32 MFMA acc

static __device__ __forceinline__ unsigned short f2bf(float f) {
  unsigned u = __float_as_uint(f);
  unsigned r = (u + 0x7fffu + ((u >> 16) & 1u)) >> 16;   // round-to-nearest-even
  return (unsigned short)r;
}

// ---------------------------------------------------------------------------
// Kernel 0a: w_off[18][512][5][5] -> A-frags Wm2:
// i = t*16384 + g*2048 + kk*512 + half*256 + l*8 + j ; c = g*64+kk*16+half*8+j
// ---------------------------------------------------------------------------
__global__ __launch_bounds__(256) void prep_wm2_kernel(
    const float* __restrict__ w_off, unsigned short* __restrict__ Wm2) {
  const int i = blockIdx.x * 256 + threadIdx.x;
  if (i >= 25 * 16384) return;
  const int j    = i & 7;
  const int l    = (i >> 3) & 31;
  const int half = (i >> 8) & 1;
  const int kk   = (i >> 9) & 3;
  const int g    = (i >> 11) & 7;
  const int t    = i >> 14;          // 0..24
  const int c = g * 64 + kk * 16 + half * 8 + j;
  float v = 0.f;
  if (l < OCONV) v = w_off[(size_t)(l * (2 * CC) + c) * 25 + t];
  Wm2[i] = f2bf(v);
}

// ---------------------------------------------------------------------------
// Kernel 0b: w_kernel[9][256][9] -> wkm A-frags (rows m=k*9+o, pad 96)
// ---------------------------------------------------------------------------
__global__ __launch_bounds__(256) void prep_wkm_kernel(
    const float* __restrict__ w_kernel, unsigned short* __restrict__ wkm) {
  const int i = blockIdx.x * 256 + threadIdx.x;
  if (i >= 3 * 16 * 2 * 32 * 8) return;
  const int j    = i & 7;
  const int r    = (i >> 3) & 31;
  const int half = (i >> 8) & 1;
  const int cb   = (i >> 9) & 15;
  const int mt   = i >> 13;
  const int m = mt * 32 + r;
  const int c = cb * 16 + half * 8 + j;
  float v = 0.f;
  if (m < 81) {
    const int k = m / 9, o = m % 9;
    v = w_kernel[(size_t)(o * CC + c) * KTAP + k];
  }
  wkm[i] = f2bf(v);
}

// ---------------------------------------------------------------------------
// Kernel 1: transpose query+support -> qsT3[n][cg][site][8ch] bf16.
// cg = c/8; c<256 query (cg 0..31), else support (cg 32..63). Sites
// 2304..2311 zeroed (OOB taps). XCD-pinned by n.
// ---------------------------------------------------------------------------
__global__ __launch_bounds__(256) void transpose_kernel(
    const float* __restrict__ support, const float* __restrict__ query,
    unsigned short* __restrict__ qsT) {
  const int bid = blockIdx.x;         // 9216 = 8n * 72pt * 16ct
  const int n    = bid & 7;           // XCD pin
  const int rest = bid >> 3;
  const int pt = rest % 72;
  const int ct = rest / 72;           // 0..15; 32-ch block
  const int p0 = pt * 32;
  const int tid = threadIdx.x;

  __shared__ float tile[32][33];

  const float* plane = ((ct < 8) ? query : support) +
                       ((size_t)n * CC + (ct & 7) * 32) * HW;
#pragma unroll
  for (int j = 0; j < 4; ++j) {
    const int idx = tid + j * 256;
    const int cc = idx >> 5, pp = idx & 31;
    tile[pp][cc] = plane[(size_t)cc * HW + p0 + pp];
  }
  __syncthreads();

  unsigned short* qn = qsT + (size_t)n * NCG * QSTR * 8;
  const int cgbase = ((ct < 8) ? 0 : 32) + (ct & 7) * 4;

  if (tid < 128) {
    const int pp  = tid & 31;
    const int cgl = tid >> 5;          // 0..3
    const float* row = &tile[pp][cgl * 8];
    uint4 w;
    w.x = (unsigned)f2bf(row[0]) | ((unsigned)f2bf(row[1]) << 16);
    w.y = (unsigned)f2bf(row[2]) | ((unsigned)f2bf(row[3]) << 16);
    w.z = (unsigned)f2bf(row[4]) | ((unsigned)f2bf(row[5]) << 16);
    w.w = (unsigned)f2bf(row[6]) | ((unsigned)f2bf(row[7]) << 16);
    *(uint4*)(qn + ((size_t)(cgbase + cgl) * QSTR + p0 + pp) * 8) = w;
  } else if (pt == 0) {
    // zero-sites: 4 cg * 8 sites * 4 dwords = 128 dwords
    const int z = tid - 128;
    const int cgl = z >> 5;
    const int zs  = 2304 + ((z >> 2) & 7);
    const int dw  = z & 3;
    ((unsigned*)qn)[((size_t)(cgbase + cgl) * QSTR + zs) * 4 + dw] = 0u;
  }
}

// ---------------------------------------------------------------------------
// Kernel 2: offset conv, no-LDS implicit GEMM with coalesced B-gathers.
// Grid 1152 = 8n * 8g * 18; block = 4 waves, wave = 32-site tile.
// Per wave: 25 taps x 4 kk = 100 MFMAs; B = 2x512B dense segments per load.
// offs_part[G1=8][N][18][HW] partials. XCD-pinned by n.
// ---------------------------------------------------------------------------
__global__ __launch_bounds__(256) void offset_conv_mfma(
    const unsigned short* __restrict__ qsT,
    const unsigned short* __restrict__ Wm2, float* __restrict__ offs_part) {
  const int bid = blockIdx.x;
  const int n  = bid & 7;            // XCD pin
  const int r  = bid >> 3;           // 0..143
  const int st4 = r % 18;
  const int g   = r / 18;            // 0..7 (64 ch each)
  const int tid = threadIdx.x;
  const int w = tid >> 6;
  const int l = tid & 63;
  const int lane31 = l & 31;
  const int half = l >> 5;
  const int s = (st4 * 4 + w) * 32 + lane31;
  const int y = s / 48, x = s % 48;

  const unsigned short* qn = qsT + (size_t)n * NCG * QSTR * 8;
  const unsigned short* abase = Wm2 + g * 2048 + half * 256 + lane31 * 8;

  f32x16 acc = {0.f, 0.f, 0.f, 0.f, 0.f, 0.f, 0.f, 0.f,
                0.f, 0.f, 0.f, 0.f, 0.f, 0.f, 0.f, 0.f};

#pragma unroll
  for (int u = 0; u < 5; ++u) {
    const int yy = y + u - 2;
#pragma unroll
    for (int v = 0; v < 5; ++v) {
      const int xx = x + v - 2;
      const bool ok = ((unsigned)yy < 48u) && ((unsigned)xx < 48u);
      const int p2 = ok ? (yy * 48 + xx) : 2304;     // zero-site if OOB
      const unsigned short* asrc = abase + (u * 5 + v) * 16384;
#pragma unroll
      for (int kk = 0; kk < 4; ++kk) {
        const int cg = g * 8 + kk * 2 + half;
        const short8 b = *(const short8*)(qn + ((size_t)cg * QSTR + p2) * 8);
        const short8 a = *(const short8*)(asrc + kk * 512);
        acc = __builtin_amdgcn_mfma_f32_32x32x16_bf16(a, b, acc, 0, 0, 0);
      }
    }
  }

  float* dst = offs_part + ((size_t)(g * NN + n) * OCONV) * HW;
#pragma unroll
  for (int r16 = 0; r16 < 16; ++r16) {
    const int o = (r16 & 3) + 8 * (r16 >> 2) + 4 * half;
    if (o < OCONV) dst[(size_t)o * HW + s] = acc[r16];
  }
}

// ---------------------------------------------------------------------------
// Kernel 3: fold split-K partials + precompute bilinear params.
// par[n][k][p][8]: {w00,w01,w10,w11 (f32), a00,a01,a10,a11 (int)}. XCD-pinned.
// ---------------------------------------------------------------------------
__global__ __launch_bounds__(256) void param_kernel(
    const float* __restrict__ offs_part, float* __restrict__ par) {
  const int n  = blockIdx.x & 7;       // XCD pin
  const int j  = blockIdx.x >> 3;      // 0..80
  const int il = j * 256 + threadIdx.x;
  const int p = il % HW;
  const int k = il / HW;
  const int y = p / WW, x = p % WW;

  float dy = 0.f, dx = 0.f;
#pragma unroll
  for (int g = 0; g < G1; ++g) {
    const float* base = offs_part + ((size_t)(g * NN + n) * OCONV + 2 * k) * HW + p;
    dy += base[0];
    dx += base[HW];
  }
  const float sy = (float)(y + k / 3 - 1) + dy;
  const float sx = (float)(x + k % 3 - 1) + dx;
  const float y0 = floorf(sy), x0 = floorf(sx);
  const float ly = sy - y0,  lx = sx - x0;
  const float y1 = y0 + 1.f, x1 = x0 + 1.f;
  const float vy0 = (y0 >= 0.f && y0 <= (float)(HH - 1)) ? 1.f : 0.f;
  const float vy1 = (y1 >= 0.f && y1 <= (float)(HH - 1)) ? 1.f : 0.f;
  const float vx0 = (x0 >= 0.f && x0 <= (float)(WW - 1)) ? 1.f : 0.f;
  const float vx1 = (x1 >= 0.f && x1 <= (float)(WW - 1)) ? 1.f : 0.f;
  const int yi0 = min(max((int)y0, 0), HH - 1);
  const int yi1 = min(max((int)y1, 0), HH - 1);
  const int xi0 = min(max((int)x0, 0), WW - 1);
  const int xi1 = min(max((int)x1, 0), WW - 1);

  float* d = par + ((size_t)n * KTAP * HW + il) * 8;
  d[0] = (1.f - ly) * (1.f - lx) * vy0 * vx0;
  d[1] = (1.f - ly) * lx * vy0 * vx1;
  d[2] = ly * (1.f - lx) * vy1 * vx0;
  d[3] = ly * lx * vy1 * vx1;
  int* di = (int*)d;
  di[4] = yi0 * WW + xi0;
  di[5] = yi0 * WW + xi1;
  di[6] = yi1 * WW + xi0;
  di[7] = yi1 * WW + xi1;
}

// ---------------------------------------------------------------------------
// Kernel 4: D[n][m][site] = sum_c wk[o][c][k] * sup[n][c][site], m=k*9+o.
// B = support cg-planes (32..63) of qsT3 — coalesced. XCD-pinned.
// ---------------------------------------------------------------------------
__global__ __launch_bounds__(256) void deform_gemm(
    const unsigned short* __restrict__ qsT, const unsigned short* __restrict__ wkm,
    float* __restrict__ D) {
  const int bid = blockIdx.x;
  const int n    = bid & 7;           // XCD pin
  const int rest = bid >> 3;          // 0..53
  const int tid = threadIdx.x;
  const int w = tid >> 6;
  const int wid = rest * 4 + w;       // 0..215
  const int st = wid % 72;            // site tile
  const int mt = wid / 72;            // m tile 0..2
  const int l = tid & 63;
  const int lane31 = l & 31;
  const int half = l >> 5;
  const int site0 = st * 32;

  const unsigned short* qn = qsT + (size_t)n * NCG * QSTR * 8;
  const unsigned short* asrc = wkm + (size_t)(half * 32 + lane31) * 8;

  f32x16 acc = {0.f, 0.f, 0.f, 0.f, 0.f, 0.f, 0.f, 0.f,
                0.f, 0.f, 0.f, 0.f, 0.f, 0.f, 0.f, 0.f};

#pragma unroll
  for (int cb = 0; cb < 16; ++cb) {
    const int cg = 32 + cb * 2 + half;
    const short8 b = *(const short8*)(qn + ((size_t)cg * QSTR + site0 + lane31) * 8);
    const short8 a = *(const short8*)(asrc + (size_t)((mt * 16 + cb) * 2) * 256);
    acc = __builtin_amdgcn_mfma_f32_32x32x16_bf16(a, b, acc, 0, 0, 0);
  }

  float* Dn = D + (size_t)n * MM * HW;
#pragma unroll
  for (int r = 0; r < 16; ++r) {
    const int m = mt * 32 + (r & 3) + 8 * (r >> 2) + 4 * half;
    Dn[(size_t)m * HW + site0 + lane31] = acc[r];
  }
}

// ---------------------------------------------------------------------------
// Kernel 5: combine + sigmoid. One thread per output element. XCD-pinned.
// ---------------------------------------------------------------------------
__global__ __launch_bounds__(256) void deform_combine(
    const float* __restrict__ D, const float* __restrict__ par,
    float* __restrict__ out) {
  const int bid = blockIdx.x;          // 648 = 81 * 8n
  const int n  = bid & 7;              // XCD pin
  const int rr = bid >> 3;             // 0..80
  const int o  = rr / 9;
  const int p  = (rr % 9) * 256 + threadIdx.x;

  const float* Dn = D + (size_t)n * MM * HW;
  const float* pb = par + ((size_t)n * KTAP * HW + p) * 8;

  float s = 0.f;
#pragma unroll
  for (int k = 0; k < KTAP; ++k) {
    const float4 wv = *(const float4*)(pb + (size_t)k * HW * 8);
    const int4  av = *(const int4*)(pb + (size_t)k * HW * 8 + 4);
    const float* base = Dn + (size_t)(k * 9 + o) * HW;
    s += wv.x * base[av.x] + wv.y * base[av.y] +
         wv.z * base[av.z] + wv.w * base[av.w];
  }
  out[((size_t)n * KTAP + o) * HW + p] = 1.f / (1.f + __expf(-s));
}

extern "C" void kernel_launch(void* const* d_in, const int* in_sizes, int n_in,
                              void* d_out, int out_size, void* d_ws, size_t ws_size,
                              hipStream_t stream) {
  const float* support  = (const float*)d_in[0];
  const float* query    = (const float*)d_in[1];
  const float* w_off    = (const float*)d_in[2];
  const float* w_kernel = (const float*)d_in[3];
  float* out = (float*)d_out;

  // ws layout (float units), ~35.8 MB total:
  // [qsT3 18.9MB][par 5.3MB][Wm2 0.82MB][wkm 0.1MB][X: offs_part 10.6MB / D 7.1MB]
  float* base = (float*)d_ws;
  unsigned short* qsT = (unsigned short*)base;                  // 8*64*QSTR*8 bf16
  float* par = base + (size_t)NN * NCG * QSTR * 8 / 2;          // NN*9*HW*8 f
  float* tail = par + (size_t)NN * KTAP * HW * 8;
  unsigned short* Wm2 = (unsigned short*)tail;                  // 409600 bf16 = 204800 f
  unsigned short* wkm = (unsigned short*)(tail + 204800);       // 49152 bf16 = 24576 f
  float* X = tail + 204800 + 24576;
  float* offs_part = X;                                         // G1*NSZ f (early)
  float* D = X;                                                 // NN*MM*HW f (late, aliases)

  prep_wm2_kernel<<<(25 * 16384 + 255) / 256, 256, 0, stream>>>(w_off, Wm2);
  prep_wkm_kernel<<<(3 * 16 * 2 * 32 * 8 + 255) / 256, 256, 0, stream>>>(w_kernel, wkm);
  transpose_kernel<<<8 * 72 * 16, 256, 0, stream>>>(support, query, qsT);
  offset_conv_mfma<<<8 * 8 * 18, 256, 0, stream>>>(qsT, Wm2, offs_part);
  param_kernel<<<81 * 8, 256, 0, stream>>>(offs_part, par);
  deform_gemm<<<54 * 8, 256, 0, stream>>>(qsT, wkm, D);   // D aliases offs_part (dead)
  deform_combine<<<81 * 8, 256, 0, stream>>>(D, par, out);
}